// Round 3
// baseline (9295.154 us; speedup 1.0000x reference)
//
#include <hip/hip_runtime.h>
#include <hip/hip_cooperative_groups.h>

namespace cg = cooperative_groups;

#define NB 256
#define NT 256

typedef __attribute__((ext_vector_type(8))) short short8;
typedef __attribute__((ext_vector_type(4))) float f32x4;

constexpr int Bz = 64, Sz = 256, Tz = 32, Ez = 512, Hz = 512, G4 = 2048, VT = 32000;

__device__ __forceinline__ unsigned short f2b(float f) {
    unsigned u; __builtin_memcpy(&u, &f, 4);
    u = (u + 0x7fffu + ((u >> 16) & 1u)) >> 16;   // RNE fp32 -> bf16
    return (unsigned short)u;
}
__device__ __forceinline__ float sgm(float x) { return 1.0f / (1.0f + __expf(-x)); }
__device__ __forceinline__ float tnh(float x) { return 1.0f - 2.0f / (1.0f + __expf(2.0f * x)); }

// ===================== 1) cooperative LSTM scan =====================
__global__ __launch_bounds__(NT, 2) void scan_kernel(
    const int* __restrict__ X, const int* __restrict__ Y,
    const float* __restrict__ emb_src, const float* __restrict__ emb_tgt,
    const float* __restrict__ eWih, const float* __restrict__ eWhh,
    const float* __restrict__ ebih, const float* __restrict__ ebhh,
    const float* __restrict__ dWih, const float* __restrict__ dWhh,
    const float* __restrict__ dbih, const float* __restrict__ dbhh,
    unsigned short* __restrict__ hbuf,   // [2 layer][2 parity][64][512] bf16
    float* __restrict__ row_sums)        // [64] (zeroed here for the FC kernel)
{
    cg::grid_group grid = cg::this_grid();

    __shared__ __align__(16) unsigned char smem[38144];
    unsigned short* xh_lds = (unsigned short*)smem;          // [16][1032] bf16 (pad +8)
    float* gates_lds = (float*)(smem + 33024);               // [4][16][16]
    float* c_lds     = (float*)(smem + 33024 + 4096);        // [16][16] fp32, persists enc->dec

    const int tid  = threadIdx.x;
    const int bid  = blockIdx.x;
    const int lay  = bid >> 7;         // 0 or 1 (pipeline stage = LSTM layer)
    const int bt   = (bid >> 5) & 3;   // batch tile (16 elems)
    const int ht   = bid & 31;         // hidden-unit tile (16 units)
    const int wave = tid >> 6;         // gate index: 0=i 1=f 2=g 3=o
    const int lane = tid & 63;
    const int nl   = lane & 15;
    const int quad = lane >> 4;
    const int srow = tid >> 4;         // staging: batch row within tile
    const int ssub = tid & 15;         // staging: 32-elem chunk
    const int bglob = bt * 16 + srow;

    // ---- init workspace (ws is re-poisoned before every launch) ----
    {
        unsigned* z = (unsigned*)hbuf;             // 2*2*64*512 bf16 = 65536 u32 words
        const int i = bid * NT + tid;
        if (i < 65536) z[i] = 0u;
        if (bid == 0 && tid < 64) row_sums[tid] = 0.0f;
    }
    c_lds[tid] = 0.0f;                             // 256 fp32 cell states
    grid.sync();

    // ---- per-wave weight cache in VGPRs: 64 rows x K=1024 (Wih || Whh), bf16 ----
    short8 wfrag[32];
    float bias_r = 0.0f;
    const int r = wave * 512 + ht * 16 + nl;       // global gate-row for this lane

    auto load_w = [&](const float* Wih, const float* Whh,
                      const float* bih, const float* bhh) {
        const float* wi = Wih + (size_t)(lay * G4 + r) * 512;
        const float* wh = Whh + (size_t)(lay * G4 + r) * 512;
#pragma unroll
        for (int kc = 0; kc < 32; ++kc) {
            const int k0 = kc * 32 + quad * 8;
            const float* s = (k0 < 512) ? (wi + k0) : (wh + (k0 - 512));
            short8 v;
#pragma unroll
            for (int j = 0; j < 8; ++j) v[j] = (short)f2b(s[j]);
            wfrag[kc] = v;
        }
        bias_r = bih[lay * G4 + r] + bhh[lay * G4 + r];
    };

    // x half: either fp32 (embedding row) or bf16 (lower layer's h); h half: bf16
    auto step = [&](const float* xrow_f, const unsigned short* xrow_b,
                    const unsigned short* hrow, unsigned short* hout) {
        {   // stage x||h -> LDS (this thread: row srow, chunk ssub of 32 elems)
            unsigned short* d = xh_lds + srow * 1032;
            short8* dx = (short8*)(d + ssub * 32);
            if (xrow_f) {
                const float4* xs = (const float4*)xrow_f;
#pragma unroll
                for (int i = 0; i < 4; ++i) {
                    float4 lo = xs[ssub * 8 + 2 * i];
                    float4 hi = xs[ssub * 8 + 2 * i + 1];
                    short8 v;
                    v[0] = (short)f2b(lo.x); v[1] = (short)f2b(lo.y);
                    v[2] = (short)f2b(lo.z); v[3] = (short)f2b(lo.w);
                    v[4] = (short)f2b(hi.x); v[5] = (short)f2b(hi.y);
                    v[6] = (short)f2b(hi.z); v[7] = (short)f2b(hi.w);
                    dx[i] = v;
                }
            } else {
                const short8* xs = (const short8*)xrow_b;
#pragma unroll
                for (int i = 0; i < 4; ++i) dx[i] = xs[ssub * 4 + i];
            }
            const short8* hs = (const short8*)hrow;
            short8* dh = (short8*)(d + 512 + ssub * 32);
#pragma unroll
            for (int i = 0; i < 4; ++i) dh[i] = hs[ssub * 4 + i];
        }
        __syncthreads();
        // gates[16 batch][16 rows] for this wave's gate, K=1024
        f32x4 acc = {0.f, 0.f, 0.f, 0.f};
        const unsigned short* ar = xh_lds + nl * 1032 + quad * 8;  // A[m=nl][k]
#pragma unroll
        for (int kc = 0; kc < 32; ++kc) {
            short8 a = *(const short8*)(ar + kc * 32);
            acc = __builtin_amdgcn_mfma_f32_16x16x32_bf16(a, wfrag[kc], acc, 0, 0, 0);
        }
        // C/D: col(n)=lane&15, row(m)=quad*4+i.  Activate + scatter to LDS.
#pragma unroll
        for (int i = 0; i < 4; ++i) {
            float v = acc[i] + bias_r;
            v = (wave == 2) ? tnh(v) : sgm(v);
            gates_lds[wave * 256 + (quad * 4 + i) * 16 + nl] = v;
        }
        __syncthreads();
        {   // c/h update: one (batch m, unit n) per thread
            const int m = srow, n = ssub;
            const float iv = gates_lds[      m * 16 + n];
            const float fv = gates_lds[256 + m * 16 + n];
            const float gv = gates_lds[512 + m * 16 + n];
            const float ov = gates_lds[768 + m * 16 + n];
            float c = c_lds[m * 16 + n];
            c = fv * c + iv * gv;
            c_lds[m * 16 + n] = c;
            const float h = ov * tnh(c);
            hout[(bt * 16 + m) * 512 + ht * 16 + n] = f2b(h);
        }
    };

    auto hb = [&](int l, int p) { return hbuf + (size_t)(l * 2 + p) * Bz * Hz; };

    // ===== encoder: pipelined rounds; L0 does step t, L1 does step t-1 =====
    load_w(eWih, eWhh, ebih, ebhh);
    for (int t = 0; t <= Sz; ++t) {
        if (lay == 0) {
            if (t < Sz) {
                const int tok = X[bglob * Sz + t];
                step(emb_src + (size_t)tok * Ez, nullptr,
                     hb(0, (t + 1) & 1) + bglob * Hz, hb(0, t & 1));
            }
        } else {
            if (t >= 1) {
                const int s = t - 1;
                step(nullptr, hb(0, s & 1) + bglob * Hz,
                     hb(1, (s + 1) & 1) + bglob * Hz, hb(1, s & 1));
            }
        }
        grid.sync();
    }

    // ===== decoder (states carry over: h via buffer parity, c in LDS) =====
    load_w(dWih, dWhh, dbih, dbhh);
    for (int t = 0; t <= Tz; ++t) {
        if (lay == 0) {
            if (t < Tz) {
                const int tok = (t == 0) ? 2 : Y[bglob * Tz + t - 1];   // BOS=2
                step(emb_tgt + (size_t)tok * Ez, nullptr,
                     hb(0, (t + 1) & 1) + bglob * Hz, hb(0, t & 1));
            }
        } else {
            if (t >= 1) {
                const int s = t - 1;
                step(nullptr, hb(0, s & 1) + bglob * Hz,
                     hb(1, (s + 1) & 1) + bglob * Hz, hb(1, s & 1));
            }
        }
        grid.sync();
    }
    // decoder L1 final h sits in hb(1, (Tz-1)&1) = hb(1,1); FC kernel reads it.
}

// ===================== 2) FC [64 x 32000] + exp-sum =====================
__global__ __launch_bounds__(NT, 1) void fc_kernel(
    const float* __restrict__ fcW, const float* __restrict__ fcb,
    const unsigned short* __restrict__ hbuf,
    float* __restrict__ logits, float* __restrict__ row_sums)
{
    __shared__ __align__(16) unsigned char smem[66816];
    unsigned short* h_lds = (unsigned short*)smem;          // [64][520] bf16
    float* row_part = (float*)(smem + 64 * 520 * 2);        // [64]

    const int tid  = threadIdx.x;
    const int bid  = blockIdx.x;
    const int wave = tid >> 6;
    const int lane = tid & 63;
    const int nl   = lane & 15;
    const int quad = lane >> 4;

    {   // stage top hidden: hb(1,1) = hbuf + 3*64*512
        const unsigned short* htop = hbuf + (size_t)3 * Bz * Hz;
        const int rr2 = tid >> 2, pp = tid & 3;
        const short8* s = (const short8*)(htop + rr2 * 512 + pp * 128);
        short8* d = (short8*)(h_lds + rr2 * 520 + pp * 128);
#pragma unroll
        for (int i = 0; i < 16; ++i) d[i] = s[i];
    }
    if (tid < 64) row_part[tid] = 0.f;
    __syncthreads();

    const int c0 = bid * 128;                 // this block's 128 vocab cols
    f32x4 acc[8];
#pragma unroll
    for (int ct = 0; ct < 8; ++ct) acc[ct] = (f32x4){0.f, 0.f, 0.f, 0.f};
    const unsigned short* ar = h_lds + (wave * 16 + nl) * 520 + quad * 8;
    const float* bb = fcW + ((size_t)c0 + nl) * 512 + quad * 8;
    for (int kc = 0; kc < 16; ++kc) {
        short8 a = *(const short8*)(ar + kc * 32);
#pragma unroll
        for (int ct = 0; ct < 8; ++ct) {
            const float* bp = bb + (size_t)ct * 16 * 512 + kc * 32;
            float4 lo = *(const float4*)(bp);
            float4 hi = *(const float4*)(bp + 4);
            short8 b;
            b[0] = (short)f2b(lo.x); b[1] = (short)f2b(lo.y);
            b[2] = (short)f2b(lo.z); b[3] = (short)f2b(lo.w);
            b[4] = (short)f2b(hi.x); b[5] = (short)f2b(hi.y);
            b[6] = (short)f2b(hi.z); b[7] = (short)f2b(hi.w);
            acc[ct] = __builtin_amdgcn_mfma_f32_16x16x32_bf16(a, b, acc[ct], 0, 0, 0);
        }
    }
    float ls[4] = {0.f, 0.f, 0.f, 0.f};
#pragma unroll
    for (int ct = 0; ct < 8; ++ct) {
        const int col = c0 + ct * 16 + nl;
        const float bias = fcb[col];
#pragma unroll
        for (int i = 0; i < 4; ++i) {
            const float lg = acc[ct][i] + bias;
            logits[(size_t)(wave * 16 + quad * 4 + i) * VT + col] = lg;
            ls[i] += __expf(lg);     // |logit| <= ~41 -> no overflow, max-shift unneeded
        }
    }
#pragma unroll
    for (int i = 0; i < 4; ++i)
        atomicAdd(&row_part[wave * 16 + quad * 4 + i], ls[i]);
    __syncthreads();
    if (tid < 64) atomicAdd(&row_sums[tid], row_part[tid]);
}

// ===================== 3) normalize: out = logits - log(sum) =====================
__global__ __launch_bounds__(NT) void norm_kernel(
    const float* __restrict__ logits, const float* __restrict__ row_sums,
    float* __restrict__ out)
{
    const int idx = blockIdx.x * NT + threadIdx.x;   // grid covers 64*32000 exactly
    const int row = idx / VT;
    out[idx] = logits[idx] - __logf(row_sums[row]);
}

extern "C" void kernel_launch(void* const* d_in, const int* in_sizes, int n_in,
                              void* d_out, int out_size, void* d_ws, size_t ws_size,
                              hipStream_t stream) {
    const int* X = (const int*)d_in[0];
    const int* Y = (const int*)d_in[1];
    const float* emb_src = (const float*)d_in[2];
    const float* emb_tgt = (const float*)d_in[3];
    const float* eWih = (const float*)d_in[4];
    const float* eWhh = (const float*)d_in[5];
    const float* ebih = (const float*)d_in[6];
    const float* ebhh = (const float*)d_in[7];
    const float* dWih = (const float*)d_in[8];
    const float* dWhh = (const float*)d_in[9];
    const float* dbih = (const float*)d_in[10];
    const float* dbhh = (const float*)d_in[11];
    const float* fcW = (const float*)d_in[12];
    const float* fcb = (const float*)d_in[13];
    float* out = (float*)d_out;

    // ws layout: [0, 256KB) bf16 h double-buffers; [256KB, +256B) row_sums;
    //            [512KB, +8.192MB) fp32 logits
    unsigned short* hbuf = (unsigned short*)d_ws;
    float* row_sums = (float*)((char*)d_ws + 262144);
    float* logits   = (float*)((char*)d_ws + 524288);

    void* args[] = {&X, &Y, &emb_src, &emb_tgt, &eWih, &eWhh, &ebih, &ebhh,
                    &dWih, &dWhh, &dbih, &dbhh, &hbuf, &row_sums};
    hipLaunchCooperativeKernel(reinterpret_cast<void*>(scan_kernel),
                               dim3(NB), dim3(NT), args, 0, stream);

    fc_kernel<<<dim3(VT / 128), dim3(NT), 0, stream>>>(fcW, fcb, hbuf, logits, row_sums);

    norm_kernel<<<dim3((Bz * VT) / NT), dim3(NT), 0, stream>>>(logits, row_sums, out);
}

// Round 4
// 1670.395 us; speedup vs baseline: 5.5646x; 5.5646x over previous
//
#include <hip/hip_runtime.h>

#define NB 256
#define NT 256

typedef __attribute__((ext_vector_type(8))) short short8;
typedef __attribute__((ext_vector_type(4))) float f32x4;

constexpr int Bz = 64, Sz = 256, Tz = 32, Ez = 512, Hz = 512, G4 = 2048, VT = 32000;

__device__ __forceinline__ unsigned short f2b(float f) {
    unsigned u; __builtin_memcpy(&u, &f, 4);
    u = (u + 0x7fffu + ((u >> 16) & 1u)) >> 16;   // RNE fp32 -> bf16
    return (unsigned short)u;
}
__device__ __forceinline__ float sgm(float x) { return 1.0f / (1.0f + __expf(-x)); }
__device__ __forceinline__ float tnh(float x) { return 1.0f - 2.0f / (1.0f + __expf(2.0f * x)); }

// ===================== 0) workspace init (stream-ordered before scan) =====================
__global__ __launch_bounds__(NT) void init_kernel(
    unsigned* __restrict__ hbuf_u32, float* __restrict__ row_sums,
    unsigned* __restrict__ bars)
{
    const int idx = blockIdx.x * NT + threadIdx.x;     // 64 blocks: covers 65536 words
#pragma unroll
    for (int i = 0; i < 4; ++i) hbuf_u32[idx * 4 + i] = 0u;
    if (blockIdx.x == 0) {
        bars[threadIdx.x] = 0u;                        // 1 KB barrier state
        if (threadIdx.x < 64) row_sums[threadIdx.x] = 0.0f;
    }
}

// ===================== 1) cooperative LSTM scan =====================
// h exchange rides relaxed agent-scope atomics (LLC-coherent, no wbl2/inv).
// 4 independent 64-block barriers (one per batch-tile group).
__global__ __launch_bounds__(NT, 2) void scan_kernel(
    const int* __restrict__ X, const int* __restrict__ Y,
    const float* __restrict__ emb_src, const float* __restrict__ emb_tgt,
    const float* __restrict__ eWih, const float* __restrict__ eWhh,
    const float* __restrict__ ebih, const float* __restrict__ ebhh,
    const float* __restrict__ dWih, const float* __restrict__ dWhh,
    const float* __restrict__ dbih, const float* __restrict__ dbhh,
    unsigned short* __restrict__ hbuf,   // [2 layer][2 parity][64][512] bf16
    unsigned* __restrict__ bars)         // [4 groups][64 u32]: +0 arrive, +32 flag
{
    __shared__ __align__(16) unsigned char smem[38144];
    unsigned short* xh_lds = (unsigned short*)smem;          // [16][1032] bf16 (pad +8)
    float* gates_lds = (float*)(smem + 33024);               // [4][16][16]
    float* c_lds     = (float*)(smem + 33024 + 4096);        // [16][16] fp32, persists enc->dec

    const int tid  = threadIdx.x;
    const int bid  = blockIdx.x;
    const int lay  = bid >> 7;         // 0 or 1 (pipeline stage = LSTM layer)
    const int bt   = (bid >> 5) & 3;   // batch tile (16 elems)
    const int ht   = bid & 31;         // hidden-unit tile (16 units)
    const int wave = tid >> 6;         // gate index: 0=i 1=f 2=g 3=o
    const int lane = tid & 63;
    const int nl   = lane & 15;
    const int quad = lane >> 4;
    const int srow = tid >> 4;         // staging: batch row within tile
    const int ssub = tid & 15;         // staging: 64B chunk of the 1KB h row
    const int bglob = bt * 16 + srow;

    unsigned* bar_arrive = bars + bt * 64;
    unsigned* bar_flag   = bars + bt * 64 + 32;
    unsigned gen = 0;

    auto barrier = [&]() {
        ++gen;
        __syncthreads();   // drains every wave's vmcnt -> h stores are at LLC
        if (tid == 0) {
            unsigned old = __hip_atomic_fetch_add(bar_arrive, 1u,
                               __ATOMIC_RELAXED, __HIP_MEMORY_SCOPE_AGENT);
            if (old == gen * 64u - 1u) {
                __hip_atomic_store(bar_flag, gen,
                                   __ATOMIC_RELAXED, __HIP_MEMORY_SCOPE_AGENT);
            } else {
                while (__hip_atomic_load(bar_flag,
                           __ATOMIC_RELAXED, __HIP_MEMORY_SCOPE_AGENT) < gen)
                    __builtin_amdgcn_s_sleep(1);
            }
        }
        __syncthreads();
    };

    c_lds[tid] = 0.0f;                             // 256 fp32 cell states
    __syncthreads();

    // ---- per-wave weight cache in VGPRs: 16 gate-rows x K=1024 (Wih||Whh), bf16 ----
    short8 wfrag[32];
    float bias_r = 0.0f;
    const int r = wave * 512 + ht * 16 + nl;       // global gate-row for this lane

    auto load_w = [&](const float* Wih, const float* Whh,
                      const float* bih, const float* bhh) {
        const float* wi = Wih + (size_t)(lay * G4 + r) * 512;
        const float* wh = Whh + (size_t)(lay * G4 + r) * 512;
#pragma unroll
        for (int kc = 0; kc < 32; ++kc) {
            const int k0 = kc * 32 + quad * 8;
            const float* s = (k0 < 512) ? (wi + k0) : (wh + (k0 - 512));
            short8 v;
#pragma unroll
            for (int j = 0; j < 8; ++j) v[j] = (short)f2b(s[j]);
            wfrag[kc] = v;
        }
        bias_r = bih[lay * G4 + r] + bhh[lay * G4 + r];
    };

    // x half: fp32 embedding row (plain loads) OR bf16 h (LLC atomic loads); h half: atomic
    auto step = [&](const float* xrow_f, const unsigned short* xrow_b,
                    const unsigned short* hrow, unsigned short* hout) {
        {   // stage x||h -> LDS (this thread: row srow, chunk ssub)
            unsigned short* d = xh_lds + srow * 1032;
            if (xrow_f) {
                short8* dx = (short8*)(d + ssub * 32);
                const float4* xs = (const float4*)xrow_f;
#pragma unroll
                for (int i = 0; i < 4; ++i) {
                    float4 lo = xs[ssub * 8 + 2 * i];
                    float4 hi = xs[ssub * 8 + 2 * i + 1];
                    short8 v;
                    v[0] = (short)f2b(lo.x); v[1] = (short)f2b(lo.y);
                    v[2] = (short)f2b(lo.z); v[3] = (short)f2b(lo.w);
                    v[4] = (short)f2b(hi.x); v[5] = (short)f2b(hi.y);
                    v[6] = (short)f2b(hi.z); v[7] = (short)f2b(hi.w);
                    dx[i] = v;
                }
            } else {
                const unsigned long long* xs = (const unsigned long long*)xrow_b;
                unsigned long long* dx = (unsigned long long*)(d + ssub * 32);
#pragma unroll
                for (int i = 0; i < 8; ++i)
                    dx[i] = __hip_atomic_load(xs + ssub * 8 + i,
                                __ATOMIC_RELAXED, __HIP_MEMORY_SCOPE_AGENT);
            }
            const unsigned long long* hs = (const unsigned long long*)hrow;
            unsigned long long* dh = (unsigned long long*)(d + 512 + ssub * 32);
#pragma unroll
            for (int i = 0; i < 8; ++i)
                dh[i] = __hip_atomic_load(hs + ssub * 8 + i,
                            __ATOMIC_RELAXED, __HIP_MEMORY_SCOPE_AGENT);
        }
        __syncthreads();
        // gates[16 batch][16 rows] for this wave's gate, K=1024
        f32x4 acc = {0.f, 0.f, 0.f, 0.f};
        const unsigned short* ar = xh_lds + nl * 1032 + quad * 8;  // A[m=nl][k]
#pragma unroll
        for (int kc = 0; kc < 32; ++kc) {
            short8 a = *(const short8*)(ar + kc * 32);
            acc = __builtin_amdgcn_mfma_f32_16x16x32_bf16(a, wfrag[kc], acc, 0, 0, 0);
        }
        // C/D: col(n)=lane&15, row(m)=quad*4+i.  Activate + scatter to LDS.
#pragma unroll
        for (int i = 0; i < 4; ++i) {
            float v = acc[i] + bias_r;
            v = (wave == 2) ? tnh(v) : sgm(v);
            gates_lds[wave * 256 + (quad * 4 + i) * 16 + nl] = v;
        }
        __syncthreads();
        if (tid < 128) {   // c/h update: (batch m, unit pair np) per thread
            const int m = tid >> 3, np = tid & 7;
            float hp[2];
#pragma unroll
            for (int j = 0; j < 2; ++j) {
                const int n = 2 * np + j;
                const float iv = gates_lds[      m * 16 + n];
                const float fv = gates_lds[256 + m * 16 + n];
                const float gv = gates_lds[512 + m * 16 + n];
                const float ov = gates_lds[768 + m * 16 + n];
                float c = c_lds[m * 16 + n];
                c = fv * c + iv * gv;
                c_lds[m * 16 + n] = c;
                hp[j] = ov * tnh(c);
            }
            const unsigned pack = (unsigned)f2b(hp[0]) | ((unsigned)f2b(hp[1]) << 16);
            unsigned* dst = (unsigned*)&hout[(bt * 16 + m) * 512 + ht * 16 + 2 * np];
            __hip_atomic_store(dst, pack, __ATOMIC_RELAXED, __HIP_MEMORY_SCOPE_AGENT);
        }
    };

    auto hb = [&](int l, int p) { return hbuf + (size_t)(l * 2 + p) * Bz * Hz; };

    // ===== encoder: pipelined rounds; L0 does step t, L1 does step t-1 =====
    load_w(eWih, eWhh, ebih, ebhh);
    for (int t = 0; t <= Sz; ++t) {
        if (lay == 0) {
            if (t < Sz) {
                const int tok = X[bglob * Sz + t];
                step(emb_src + (size_t)tok * Ez, nullptr,
                     hb(0, (t + 1) & 1) + bglob * Hz, hb(0, t & 1));
            }
        } else {
            if (t >= 1) {
                const int s = t - 1;
                step(nullptr, hb(0, s & 1) + bglob * Hz,
                     hb(1, (s + 1) & 1) + bglob * Hz, hb(1, s & 1));
            }
        }
        barrier();
    }

    // ===== decoder (states carry over: h via buffer parity, c in LDS) =====
    load_w(dWih, dWhh, dbih, dbhh);
    for (int t = 0; t <= Tz; ++t) {
        if (lay == 0) {
            if (t < Tz) {
                const int tok = (t == 0) ? 2 : Y[bglob * Tz + t - 1];   // BOS=2
                step(emb_tgt + (size_t)tok * Ez, nullptr,
                     hb(0, (t + 1) & 1) + bglob * Hz, hb(0, t & 1));
            }
        } else {
            if (t >= 1) {
                const int s = t - 1;
                step(nullptr, hb(0, s & 1) + bglob * Hz,
                     hb(1, (s + 1) & 1) + bglob * Hz, hb(1, s & 1));
            }
        }
        barrier();
    }
    // decoder L1 final h sits in hb(1,1); FC kernel reads it (kernel-boundary sync).
}

// ===================== 2) FC [64 x 32000] + exp-sum =====================
__global__ __launch_bounds__(NT, 1) void fc_kernel(
    const float* __restrict__ fcW, const float* __restrict__ fcb,
    const unsigned short* __restrict__ hbuf,
    float* __restrict__ logits, float* __restrict__ row_sums)
{
    __shared__ __align__(16) unsigned char smem[66816];
    unsigned short* h_lds = (unsigned short*)smem;          // [64][520] bf16
    float* row_part = (float*)(smem + 64 * 520 * 2);        // [64]

    const int tid  = threadIdx.x;
    const int bid  = blockIdx.x;
    const int wave = tid >> 6;
    const int lane = tid & 63;
    const int nl   = lane & 15;
    const int quad = lane >> 4;

    {   // stage top hidden: hb(1,1) = hbuf + 3*64*512
        const unsigned short* htop = hbuf + (size_t)3 * Bz * Hz;
        const int rr2 = tid >> 2, pp = tid & 3;
        const short8* s = (const short8*)(htop + rr2 * 512 + pp * 128);
        short8* d = (short8*)(h_lds + rr2 * 520 + pp * 128);
#pragma unroll
        for (int i = 0; i < 16; ++i) d[i] = s[i];
    }
    if (tid < 64) row_part[tid] = 0.f;
    __syncthreads();

    const int c0 = bid * 128;                 // this block's 128 vocab cols
    f32x4 acc[8];
#pragma unroll
    for (int ct = 0; ct < 8; ++ct) acc[ct] = (f32x4){0.f, 0.f, 0.f, 0.f};
    const unsigned short* ar = h_lds + (wave * 16 + nl) * 520 + quad * 8;
    const float* bb = fcW + ((size_t)c0 + nl) * 512 + quad * 8;
    for (int kc = 0; kc < 16; ++kc) {
        short8 a = *(const short8*)(ar + kc * 32);
#pragma unroll
        for (int ct = 0; ct < 8; ++ct) {
            const float* bp = bb + (size_t)ct * 16 * 512 + kc * 32;
            float4 lo = *(const float4*)(bp);
            float4 hi = *(const float4*)(bp + 4);
            short8 b;
            b[0] = (short)f2b(lo.x); b[1] = (short)f2b(lo.y);
            b[2] = (short)f2b(lo.z); b[3] = (short)f2b(lo.w);
            b[4] = (short)f2b(hi.x); b[5] = (short)f2b(hi.y);
            b[6] = (short)f2b(hi.z); b[7] = (short)f2b(hi.w);
            acc[ct] = __builtin_amdgcn_mfma_f32_16x16x32_bf16(a, b, acc[ct], 0, 0, 0);
        }
    }
    float ls[4] = {0.f, 0.f, 0.f, 0.f};
#pragma unroll
    for (int ct = 0; ct < 8; ++ct) {
        const int col = c0 + ct * 16 + nl;
        const float bias = fcb[col];
#pragma unroll
        for (int i = 0; i < 4; ++i) {
            const float lg = acc[ct][i] + bias;
            logits[(size_t)(wave * 16 + quad * 4 + i) * VT + col] = lg;
            ls[i] += __expf(lg);     // |logit| <= ~41 -> no overflow, max-shift unneeded
        }
    }
#pragma unroll
    for (int i = 0; i < 4; ++i)
        atomicAdd(&row_part[wave * 16 + quad * 4 + i], ls[i]);
    __syncthreads();
    if (tid < 64) atomicAdd(&row_sums[tid], row_part[tid]);
}

// ===================== 3) normalize: out = logits - log(sum) =====================
__global__ __launch_bounds__(NT) void norm_kernel(
    const float* __restrict__ logits, const float* __restrict__ row_sums,
    float* __restrict__ out)
{
    const int idx = blockIdx.x * NT + threadIdx.x;   // grid covers 64*32000 exactly
    const int row = idx / VT;
    out[idx] = logits[idx] - __logf(row_sums[row]);
}

extern "C" void kernel_launch(void* const* d_in, const int* in_sizes, int n_in,
                              void* d_out, int out_size, void* d_ws, size_t ws_size,
                              hipStream_t stream) {
    const int* X = (const int*)d_in[0];
    const int* Y = (const int*)d_in[1];
    const float* emb_src = (const float*)d_in[2];
    const float* emb_tgt = (const float*)d_in[3];
    const float* eWih = (const float*)d_in[4];
    const float* eWhh = (const float*)d_in[5];
    const float* ebih = (const float*)d_in[6];
    const float* ebhh = (const float*)d_in[7];
    const float* dWih = (const float*)d_in[8];
    const float* dWhh = (const float*)d_in[9];
    const float* dbih = (const float*)d_in[10];
    const float* dbhh = (const float*)d_in[11];
    const float* fcW = (const float*)d_in[12];
    const float* fcb = (const float*)d_in[13];
    float* out = (float*)d_out;

    // ws layout: [0,256KB) bf16 h buffers; [256KB,+256B) row_sums;
    //            [260KB,+1KB) barrier state; [512KB,+8.192MB) fp32 logits
    unsigned short* hbuf = (unsigned short*)d_ws;
    float* row_sums = (float*)((char*)d_ws + 262144);
    unsigned* bars  = (unsigned*)((char*)d_ws + 266240);
    float* logits   = (float*)((char*)d_ws + 524288);

    init_kernel<<<dim3(64), dim3(NT), 0, stream>>>((unsigned*)hbuf, row_sums, bars);

    void* args[] = {&X, &Y, &emb_src, &emb_tgt, &eWih, &eWhh, &ebih, &ebhh,
                    &dWih, &dWhh, &dbih, &dbhh, &hbuf, &bars};
    hipLaunchCooperativeKernel(reinterpret_cast<void*>(scan_kernel),
                               dim3(NB), dim3(NT), args, 0, stream);

    fc_kernel<<<dim3(VT / 128), dim3(NT), 0, stream>>>(fcW, fcb, hbuf, logits, row_sums);

    norm_kernel<<<dim3((Bz * VT) / NT), dim3(NT), 0, stream>>>(logits, row_sums, out);
}